// Round 1
// baseline (570.914 us; speedup 1.0000x reference)
//
#include <hip/hip_runtime.h>
#include <cstdint>

#define EPS 1e-5f
#define INV_NTOT (1.0f / 1048576.0f)   // 1/(16*256*256)

// ws layout (float offsets):
//   [0, 1M)        h0  : conv1 output (16,1,256,256)
//   [1M, 2M)       fz  : fuzzify output
//   [2M, 2M+56)    stats: [0]=sum,[1]=sumsq, [2..10]=S[9], [11..55]=Q[45]
#define FZ_OFF  1048576
#define ST_OFF  2097152

__device__ __forceinline__ void dev_atomic_add(float* p, float v) {
    __hip_atomic_fetch_add(p, v, __ATOMIC_RELAXED, __HIP_MEMORY_SCOPE_AGENT);
}

// ---------------- K1: conv1 (64->1 ch, 3x3 SAME) + bn1 stat accumulation ----
// grid 512 = 16 n * 32 htiles ; block 512 (8 waves). Tile: 8 output rows x 256
// cols; stages 10 input rows (+1 halo each side) per channel into LDS.
// XCD-chunked swizzle: consecutive blockIdx round-robin the 8 XCDs, so give
// each XCD a contiguous chunk of 64 tiles. With 2 blocks/CU the whole chunk is
// resident at once -> halo rows shared by vertically-adjacent tiles hit the
// same XCD's L2 instead of being fetched twice from HBM.
__global__ __launch_bounds__(512) void k1_conv1(
    const float* __restrict__ x, const float* __restrict__ w1,
    float* __restrict__ h0, float* __restrict__ stats)
{
    __shared__ float tile[10][264];   // interior cols [4..259], zeros at 3/260
    __shared__ float red_s[8], red_q[8];

    const int tid   = threadIdx.x;
    const int b     = blockIdx.x;                 // 0..511
    const int lin   = ((b & 7) << 6) + (b >> 3);  // bijective: 512 % 8 == 0
    const int n     = lin >> 5;
    const int ht    = lin & 31;
    const int h0b   = ht << 3;

    const int t     = tid & 255;      // output column
    const int ohb   = (tid >> 8) << 2; // 0 or 4: this thread's 4 output rows
    const int rs    = tid >> 6;       // staging row 0..7
    const int col4  = (tid & 63) << 2;

    float acc0 = 0.f, acc1 = 0.f, acc2 = 0.f, acc3 = 0.f;

    if (tid < 10) { tile[tid][3] = 0.f; tile[tid][260] = 0.f; }

    const float* xn = x + ((size_t)n << 22);   // n * 64 * 65536

    for (int c = 0; c < 64; ++c) {
        __syncthreads();
        // stage rows 0..9  (global rows h0b-1 .. h0b+8), zero-padded
        {
            int g = h0b - 1 + rs;
            float4 v = make_float4(0.f, 0.f, 0.f, 0.f);
            if ((unsigned)g < 256u)
                v = *(const float4*)(xn + ((size_t)c << 16) + (g << 8) + col4);
            *(float4*)&tile[rs][4 + col4] = v;
            if (rs < 2) {
                int g2 = h0b + 7 + rs;
                float4 v2 = make_float4(0.f, 0.f, 0.f, 0.f);
                if ((unsigned)g2 < 256u)
                    v2 = *(const float4*)(xn + ((size_t)c << 16) + (g2 << 8) + col4);
                *(float4*)&tile[8 + rs][4 + col4] = v2;
            }
        }
        __syncthreads();

        float wc[9];
        #pragma unroll
        for (int k = 0; k < 9; ++k) wc[k] = w1[c * 9 + k];

        #pragma unroll
        for (int rr = 0; rr < 6; ++rr) {
            const int sr = ohb + rr;
            float vm = tile[sr][3 + t];
            float v0 = tile[sr][4 + t];
            float vp = tile[sr][5 + t];
            #pragma unroll
            for (int di = 0; di < 3; ++di) {
                const int l = rr - di;   // local output row
                if (l >= 0 && l < 4) {
                    float contrib = wc[di * 3 + 0] * vm + wc[di * 3 + 1] * v0
                                  + wc[di * 3 + 2] * vp;
                    if      (l == 0) acc0 += contrib;
                    else if (l == 1) acc1 += contrib;
                    else if (l == 2) acc2 += contrib;
                    else             acc3 += contrib;
                }
            }
        }
    }

    // write h0 (conv1_b omitted: constant bias cancels in bn1)
    size_t ob = ((size_t)n << 16) + (size_t)((h0b + ohb) << 8) + t;
    h0[ob]       = acc0;
    h0[ob + 256] = acc1;
    h0[ob + 512] = acc2;
    h0[ob + 768] = acc3;

    float s  = acc0 + acc1 + acc2 + acc3;
    float sq = acc0 * acc0 + acc1 * acc1 + acc2 * acc2 + acc3 * acc3;
    #pragma unroll
    for (int o = 32; o > 0; o >>= 1) {
        s  += __shfl_down(s,  o, 64);
        sq += __shfl_down(sq, o, 64);
    }
    const int wave = tid >> 6, lane = tid & 63;
    if (lane == 0) { red_s[wave] = s; red_q[wave] = sq; }
    __syncthreads();
    if (tid == 0) {
        float S = 0.f, Q = 0.f;
        #pragma unroll
        for (int i = 0; i < 8; ++i) { S += red_s[i]; Q += red_q[i]; }
        dev_atomic_add(&stats[0], S);
        dev_atomic_add(&stats[1], Q);
    }
}

// ---------------- K34: bn1 apply + fuzzify + shifted stats (fused) ----------
// grid 1024 = 16 n * 8*8 tiles of 32x32 ; block 256.
// fuzzify is pointwise, so we compute it for a 34x34 region (1-px halo,
// recomputed at tile borders, zero outside the image) into LDS. The interior
// 32x32 is written to fz for k6, and the S[9]/Q[45] shifted sums/correlations
// are accumulated straight from the LDS tile -- this removes the former
// separate k4 pass over fz. Row stride 37 floats: (37*a + 4*b) mod 32 is
// ~2-way max for the (row=tid>>3, col=(tid&7)*4) access -> conflict-free-ish
// (stride 36 was an 8-way conflict: (36a+4b) mod 32 = 4*((a+b) mod 8)).
__global__ __launch_bounds__(256) void k34_fuzzify_stats(
    const float* __restrict__ h0, const float* __restrict__ bn1_g,
    const float* __restrict__ bn1_b, const float* __restrict__ lb,
    const float* __restrict__ ub, float* __restrict__ fz,
    float* __restrict__ stats)
{
    __shared__ float fzt[34][37];
    __shared__ float red[4][54];

    const int bid = blockIdx.x;
    const int n   = bid >> 6;
    const int th  = (bid >> 3) & 7;
    const int tw  = bid & 7;
    const int h0b = th << 5, w0b = tw << 5;
    const int tid = threadIdx.x;

    const float mean = stats[0] * INV_NTOT;
    const float var  = stats[1] * INV_NTOT - mean * mean;
    const float rstd = rsqrtf(var + EPS);
    const float A    = bn1_g[0] * rstd;
    const float B    = bn1_b[0] - mean * A;

    float lbv[4], ubv[4];
    #pragma unroll
    for (int f = 0; f < 4; ++f) { lbv[f] = lb[f]; ubv[f] = ub[f]; }

    const float* hn = h0 + ((size_t)n << 16);
    for (int i = tid; i < 34 * 34; i += 256) {
        const int rr = i / 34, cc = i - rr * 34;
        const int gh = h0b + rr - 1, gw = w0b + cc - 1;
        float val = 0.f;
        if ((unsigned)gh < 256u && (unsigned)gw < 256u) {
            float xv = A * hn[(gh << 8) + gw] + B;
            float fuzz = 0.f;
            #pragma unroll
            for (int f = 0; f < 4; ++f) {
                float ld = xv - lbv[f];
                float ud = ubv[f] - xv;
                bool inr  = (ld > 0.f) && (ud > 0.f);
                bool outr = (ld < 0.f) || (ud < 0.f);
                float xr  = 2.f * lbv[f] - xv;
                float u2  = ubv[f] - xr;
                float e1  = __expf(-0.5f * ld * ld);
                float cin  = e1 + __expf(-0.5f * ud * ud);
                float cout = e1 + __expf(-0.5f * u2 * u2);
                fuzz += inr ? cin : (outr ? cout : 0.f);
                xv = outr ? xr : xv;
            }
            val = fuzz;
        }
        fzt[rr][cc] = val;
    }
    __syncthreads();

    // write interior 32x32 to fz (this thread: row r, cols q..q+3)
    const int r = tid >> 3, q = (tid & 7) << 2;
    float4 o = make_float4(fzt[r + 1][q + 1], fzt[r + 1][q + 2],
                           fzt[r + 1][q + 3], fzt[r + 1][q + 4]);
    *(float4*)(fz + ((size_t)n << 16) + (size_t)((h0b + r) << 8) + w0b + q) = o;

    // shifted sums S[9] & correlations Q[45] on the same 4 interior pixels
    float s9[9], q45[45];
    #pragma unroll
    for (int i = 0; i < 9; ++i)  s9[i]  = 0.f;
    #pragma unroll
    for (int i = 0; i < 45; ++i) q45[i] = 0.f;

    #pragma unroll
    for (int k = 0; k < 4; ++k) {
        float v[9];
        #pragma unroll
        for (int di = 0; di < 3; ++di)
            #pragma unroll
            for (int dj = 0; dj < 3; ++dj)
                v[di * 3 + dj] = fzt[r + di][q + k + dj];
        int idx = 0;
        #pragma unroll
        for (int a = 0; a < 9; ++a) {
            s9[a] += v[a];
            #pragma unroll
            for (int bb = a; bb < 9; ++bb) q45[idx++] += v[a] * v[bb];
        }
    }

    const int wave = tid >> 6, lane = tid & 63;
    float vals[54];
    #pragma unroll
    for (int i = 0; i < 9; ++i)  vals[i]     = s9[i];
    #pragma unroll
    for (int i = 0; i < 45; ++i) vals[9 + i] = q45[i];
    #pragma unroll
    for (int i = 0; i < 54; ++i) {
        float vv = vals[i];
        #pragma unroll
        for (int o2 = 32; o2 > 0; o2 >>= 1) vv += __shfl_down(vv, o2, 64);
        if (lane == 0) red[wave][i] = vv;
    }
    __syncthreads();
    if (tid < 54) {
        float tot = red[0][tid] + red[1][tid] + red[2][tid] + red[3][tid];
        dev_atomic_add(&stats[2 + tid], tot);
    }
}

// ---------------- K6: conv2 (1->64 ch, 3x3 SAME) + bn2 (scale/bias inline) --
// grid 1024 = 16 n * 8 * 8 tiles of 32x32 ; block 256, 4 px/thread (float4).
// Former k5 folded in: 64 threads/block redundantly derive the per-channel
// bn2 scale/bias from the analytic stats (~100 FMA each, inputs L2-cached).
__global__ __launch_bounds__(256) void k6_conv2(
    const float* __restrict__ fz, const float* __restrict__ w2,
    const float* __restrict__ bn2_g, const float* __restrict__ bn2_b,
    const float* __restrict__ stats, float* __restrict__ out)
{
    __shared__ float tile[34][37];
    __shared__ float sc_s[64], bi_s[64];
    const int bid = blockIdx.x;
    const int n   = bid >> 6;
    const int th  = (bid >> 3) & 7;
    const int tw  = bid & 7;
    const int h0b = th << 5, w0b = tw << 5;
    const int tid = threadIdx.x;

    const float* f = fz + ((size_t)n << 16);
    for (int i = tid; i < 34 * 34; i += 256) {
        int rr = i / 34, cc = i - rr * 34;
        int gh = h0b + rr - 1, gw = w0b + cc - 1;
        tile[rr][cc] = ((unsigned)gh < 256u && (unsigned)gw < 256u)
                     ? f[(gh << 8) + gw] : 0.f;
    }

    if (tid < 64) {
        const int c = tid;
        float w[9];
        #pragma unroll
        for (int k = 0; k < 9; ++k) w[k] = w2[c * 9 + k];
        float P = 0.f;
        #pragma unroll
        for (int k = 0; k < 9; ++k) P += w[k] * stats[2 + k];
        P *= INV_NTOT;
        float QF = 0.f;
        int idx = 0;
        #pragma unroll
        for (int a = 0; a < 9; ++a)
            #pragma unroll
            for (int bb = a; bb < 9; ++bb) {
                float qv = stats[11 + idx]; idx++;
                QF += w[a] * w[bb] * qv * ((a == bb) ? 1.f : 2.f);
            }
        QF *= INV_NTOT;
        // conv2_b cancels in bn2 (constant shift removed by mean subtraction)
        float varc  = QF - P * P;
        float scale = bn2_g[c] * rsqrtf(varc + EPS);
        sc_s[c] = scale;
        bi_s[c] = bn2_b[c] - P * scale;
    }
    __syncthreads();

    const int r = tid >> 3, q = tid & 7;
    float v[3][6];
    #pragma unroll
    for (int di = 0; di < 3; ++di)
        #pragma unroll
        for (int j = 0; j < 6; ++j)
            v[di][j] = tile[r + di][(q << 2) + j];

    const size_t ob = ((size_t)n << 22) + (size_t)((h0b + r) << 8) + w0b + (q << 2);
    for (int c = 0; c < 64; ++c) {
        float wk[9];
        #pragma unroll
        for (int k = 0; k < 9; ++k) wk[k] = w2[c * 9 + k];
        const float sc = sc_s[c], bi = bi_s[c];
        float4 o;
        float* op = &o.x;
        #pragma unroll
        for (int k = 0; k < 4; ++k) {
            float y = 0.f;
            #pragma unroll
            for (int di = 0; di < 3; ++di)
                y += wk[di * 3 + 0] * v[di][k]
                   + wk[di * 3 + 1] * v[di][k + 1]
                   + wk[di * 3 + 2] * v[di][k + 2];
            op[k] = y * sc + bi;
        }
        *(float4*)(out + ob + ((size_t)c << 16)) = o;
    }
}

extern "C" void kernel_launch(void* const* d_in, const int* in_sizes, int n_in,
                              void* d_out, int out_size, void* d_ws, size_t ws_size,
                              hipStream_t stream)
{
    const float* x  = (const float*)d_in[0];
    const float* w1 = (const float*)d_in[1];
    // d_in[2] = conv1_b : cancels under bn1 (training mode) -> unused
    const float* w2 = (const float*)d_in[3];
    // d_in[4] = conv2_b : cancels under bn2 -> unused
    const float* g1 = (const float*)d_in[5];
    const float* b1 = (const float*)d_in[6];
    const float* g2 = (const float*)d_in[7];
    const float* b2 = (const float*)d_in[8];
    const float* lb = (const float*)d_in[9];
    const float* ub = (const float*)d_in[10];

    float* ws  = (float*)d_ws;
    float* h0  = ws;
    float* fz  = ws + FZ_OFF;
    float* st  = ws + ST_OFF;
    float* out = (float*)d_out;

    hipMemsetAsync(st, 0, 56 * sizeof(float), stream);            // sum,sumsq,S,Q
    k1_conv1         <<<dim3(512),  dim3(512), 0, stream>>>(x, w1, h0, st);
    k34_fuzzify_stats<<<dim3(1024), dim3(256), 0, stream>>>(h0, g1, b1, lb, ub, fz, st);
    k6_conv2         <<<dim3(1024), dim3(256), 0, stream>>>(fz, w2, g2, b2, st, out);
}

// Round 4
// 502.019 us; speedup vs baseline: 1.1372x; 1.1372x over previous
//
#include <hip/hip_runtime.h>
#include <cstdint>

#define EPS 1e-5f
#define INV_NTOT (1.0f / 1048576.0f)   // 1/(16*256*256)

typedef float f4_vec __attribute__((ext_vector_type(4)));

// ws layout (float offsets):
//   [0, 1M)        h0  : conv1 output (16,1,256,256)
//   [1M, 2M)       fz  : fuzzify output
//   [2M, 2M+56)    stats: [0]=sum,[1]=sumsq, [2..10]=S[9], [11..55]=Q[45]
#define FZ_OFF  1048576
#define ST_OFF  2097152

__device__ __forceinline__ void dev_atomic_add(float* p, float v) {
    __hip_atomic_fetch_add(p, v, __ATOMIC_RELAXED, __HIP_MEMORY_SCOPE_AGENT);
}

// ---------------- K1: conv1 (64->1 ch, 3x3 SAME) + bn1 stat accumulation ----
// grid 512 = 16 n * 32 htiles ; block 512 (8 waves). Each wave owns 8 input
// channels and convolves them entirely in registers: horizontal neighbors via
// 2 __shfl per row, vertical taps via static unroll (input row r feeds output
// rows r+1,r,r-1). No LDS and no barriers in the 64-channel hot loop (the old
// version paid 128 __syncthreads + ~1152 scalar ds_reads/thread). One
// cross-wave reduction at the end through a 32KB LDS buffer (3 barriers).
// XCD-chunked blockIdx swizzle keeps vertically-adjacent strips (shared halo
// rows) on the same XCD's L2.
__global__ __launch_bounds__(512, 4) void k1_conv1(
    const float* __restrict__ x, const float* __restrict__ w1,
    float* __restrict__ h0, float* __restrict__ stats)
{
    __shared__ float part[8][4][256];   // [wave][row-of-half][col] = 32 KB
    __shared__ float red_s[8], red_q[8];

    const int tid  = threadIdx.x;
    const int wv   = tid >> 6;          // wave 0..7 -> channels wv*8 .. wv*8+7
    const int lane = tid & 63;          // cols 4*lane .. 4*lane+3

    const int b   = blockIdx.x;                   // 0..511
    const int lin = ((b & 7) << 6) + (b >> 3);    // bijective: 512 % 8 == 0
    const int n   = lin >> 5;
    const int h0b = (lin & 31) << 3;

    float acc[8][4];
    #pragma unroll
    for (int o = 0; o < 8; ++o)
        #pragma unroll
        for (int k = 0; k < 4; ++k) acc[o][k] = 0.f;

    const float* xn = x + ((size_t)n << 22) + ((size_t)(wv << 3) << 16)
                    + (lane << 2);

    for (int cc = 0; cc < 8; ++cc) {
        const float* wcp = w1 + ((wv << 3) + cc) * 9;   // wave-uniform -> s_load
        float wc[9];
        #pragma unroll
        for (int k = 0; k < 9; ++k) wc[k] = wcp[k];
        const float* xc = xn + ((size_t)cc << 16);

        #pragma unroll
        for (int r = -1; r <= 8; ++r) {
            const int g = h0b + r;
            float4 v = make_float4(0.f, 0.f, 0.f, 0.f);
            if ((unsigned)g < 256u) v = *(const float4*)(xc + (g << 8));
            float lf = __shfl_up(v.w, 1, 64);
            float rt = __shfl_down(v.x, 1, 64);
            if (lane == 0)  lf = 0.f;     // col -1 zero pad
            if (lane == 63) rt = 0.f;     // col 256 zero pad
            #pragma unroll
            for (int di = 0; di < 3; ++di) {
                const int o = r + 1 - di;   // output row fed by (r, di)
                if (o >= 0 && o < 8) {
                    const float w0 = wc[di * 3 + 0];
                    const float w1v = wc[di * 3 + 1];
                    const float w2v = wc[di * 3 + 2];
                    acc[o][0] += w0 * lf  + w1v * v.x + w2v * v.y;
                    acc[o][1] += w0 * v.x + w1v * v.y + w2v * v.z;
                    acc[o][2] += w0 * v.y + w1v * v.z + w2v * v.w;
                    acc[o][3] += w0 * v.z + w1v * v.w + w2v * rt;
                }
            }
        }
    }

    // cross-wave reduction, two halves of 4 rows (keeps LDS at 32 KB)
    float s = 0.f, sq = 0.f;
    #pragma unroll
    for (int half = 0; half < 2; ++half) {
        __syncthreads();    // for half=1: previous half's reads complete
        #pragma unroll
        for (int o = 0; o < 4; ++o)
            *(float4*)&part[wv][o][lane << 2] = *(float4*)acc[(half << 2) + o];
        __syncthreads();
        #pragma unroll
        for (int k = 0; k < 2; ++k) {
            const int idx = tid + (k << 9);    // 0..1023
            const int ro  = idx >> 8;          // 0..3
            const int co  = idx & 255;
            float v = 0.f;
            #pragma unroll
            for (int w = 0; w < 8; ++w) v += part[w][ro][co];
            // conv1_b omitted: constant bias cancels in bn1 (training mode)
            h0[((size_t)n << 16) + ((size_t)(h0b + (half << 2) + ro) << 8) + co] = v;
            s  += v;
            sq += v * v;
        }
    }

    #pragma unroll
    for (int o = 32; o > 0; o >>= 1) {
        s  += __shfl_down(s,  o, 64);
        sq += __shfl_down(sq, o, 64);
    }
    if (lane == 0) { red_s[wv] = s; red_q[wv] = sq; }
    __syncthreads();
    if (tid == 0) {
        float S = 0.f, Q = 0.f;
        #pragma unroll
        for (int i = 0; i < 8; ++i) { S += red_s[i]; Q += red_q[i]; }
        dev_atomic_add(&stats[0], S);
        dev_atomic_add(&stats[1], Q);
    }
}

// ---------------- K3: bn1 apply + fuzzify (elementwise, float4) -------------
__global__ __launch_bounds__(256) void k3_fuzzify(
    const float* __restrict__ h0, const float* __restrict__ stats,
    const float* __restrict__ bn1_g, const float* __restrict__ bn1_b,
    const float* __restrict__ lb, const float* __restrict__ ub,
    float* __restrict__ fz)
{
    const int i = blockIdx.x * 256 + threadIdx.x;   // float4 index (262144)

    const float mean = stats[0] * INV_NTOT;
    const float var  = stats[1] * INV_NTOT - mean * mean;
    const float rstd = rsqrtf(var + EPS);
    const float A    = bn1_g[0] * rstd;
    const float B    = bn1_b[0] - mean * A;

    float lbv[4], ubv[4];
    #pragma unroll
    for (int f = 0; f < 4; ++f) { lbv[f] = lb[f]; ubv[f] = ub[f]; }

    float4 hv = *(const float4*)(h0 + (size_t)i * 4);
    float in[4] = { hv.x, hv.y, hv.z, hv.w };
    float res[4];
    #pragma unroll
    for (int k = 0; k < 4; ++k) {
        float xv = A * in[k] + B;
        float fuzz = 0.f;
        #pragma unroll
        for (int f = 0; f < 4; ++f) {
            float ld = xv - lbv[f];
            float ud = ubv[f] - xv;
            bool inr  = (ld > 0.f) && (ud > 0.f);
            bool outr = (ld < 0.f) || (ud < 0.f);
            float xr  = 2.f * lbv[f] - xv;
            float u2  = ubv[f] - xr;
            float e1  = __expf(-0.5f * ld * ld);
            float cin  = e1 + __expf(-0.5f * ud * ud);
            float cout = e1 + __expf(-0.5f * u2 * u2);
            fuzz += inr ? cin : (outr ? cout : 0.f);
            xv = outr ? xr : xv;
        }
        res[k] = fuzz;
    }
    *(float4*)(fz + (size_t)i * 4) = make_float4(res[0], res[1], res[2], res[3]);
}

// ---------------- K4: shifted sums S[9] & correlations Q[45] over fz --------
__global__ __launch_bounds__(256) void k4_stats(
    const float* __restrict__ fz, float* __restrict__ stats)
{
    float s9[9], q45[45];
    #pragma unroll
    for (int i = 0; i < 9; ++i)  s9[i]  = 0.f;
    #pragma unroll
    for (int i = 0; i < 45; ++i) q45[i] = 0.f;

    const int base = blockIdx.x * 256 + threadIdx.x;
    for (int k = 0; k < 16; ++k) {
        int p = base + k * 65536;
        int w = p & 255, h = (p >> 8) & 255, n = p >> 16;
        const float* f = fz + ((size_t)n << 16);
        float v[9];
        #pragma unroll
        for (int di = 0; di < 3; ++di)
            #pragma unroll
            for (int dj = 0; dj < 3; ++dj) {
                int hh = h + di - 1, ww = w + dj - 1;
                v[di * 3 + dj] = ((unsigned)hh < 256u && (unsigned)ww < 256u)
                               ? f[(hh << 8) + ww] : 0.f;
            }
        int idx = 0;
        #pragma unroll
        for (int a = 0; a < 9; ++a) {
            s9[a] += v[a];
            #pragma unroll
            for (int b = a; b < 9; ++b) q45[idx++] += v[a] * v[b];
        }
    }

    __shared__ float red[4][54];
    const int wave = threadIdx.x >> 6, lane = threadIdx.x & 63;
    float vals[54];
    #pragma unroll
    for (int i = 0; i < 9; ++i)  vals[i]     = s9[i];
    #pragma unroll
    for (int i = 0; i < 45; ++i) vals[9 + i] = q45[i];
    #pragma unroll
    for (int i = 0; i < 54; ++i) {
        float vv = vals[i];
        #pragma unroll
        for (int o = 32; o > 0; o >>= 1) vv += __shfl_down(vv, o, 64);
        if (lane == 0) red[wave][i] = vv;
    }
    __syncthreads();
    if (threadIdx.x < 54) {
        float tot = red[0][threadIdx.x] + red[1][threadIdx.x]
                  + red[2][threadIdx.x] + red[3][threadIdx.x];
        dev_atomic_add(&stats[2 + threadIdx.x], tot);
    }
}

// ---------------- K6: conv2 (1->64 ch, 3x3 SAME) + bn2 (scale/bias inline) --
// grid 1024 = 16 n * 8 * 8 tiles of 32x32 ; block 256, 4 px/thread (float4).
// bn2 scale/bias derived per-block from analytic stats (~100 FMA on 64
// threads, inputs L2-cached). Output uses NONTEMPORAL stores: 268 MB of `out`
// would otherwise sweep the 256 MB L3 and evict the L3-resident fz mid-kernel.
__global__ __launch_bounds__(256) void k6_conv2(
    const float* __restrict__ fz, const float* __restrict__ w2,
    const float* __restrict__ bn2_g, const float* __restrict__ bn2_b,
    const float* __restrict__ stats, float* __restrict__ out)
{
    __shared__ float tile[34][37];
    __shared__ float sc_s[64], bi_s[64];
    const int bid = blockIdx.x;
    const int n   = bid >> 6;
    const int th  = (bid >> 3) & 7;
    const int tw  = bid & 7;
    const int h0b = th << 5, w0b = tw << 5;
    const int tid = threadIdx.x;

    const float* f = fz + ((size_t)n << 16);
    for (int i = tid; i < 34 * 34; i += 256) {
        int rr = i / 34, cc = i - rr * 34;
        int gh = h0b + rr - 1, gw = w0b + cc - 1;
        tile[rr][cc] = ((unsigned)gh < 256u && (unsigned)gw < 256u)
                     ? f[(gh << 8) + gw] : 0.f;
    }

    if (tid < 64) {
        const int c = tid;
        float w[9];
        #pragma unroll
        for (int k = 0; k < 9; ++k) w[k] = w2[c * 9 + k];
        float P = 0.f;
        #pragma unroll
        for (int k = 0; k < 9; ++k) P += w[k] * stats[2 + k];
        P *= INV_NTOT;
        float QF = 0.f;
        int idx = 0;
        #pragma unroll
        for (int a = 0; a < 9; ++a)
            #pragma unroll
            for (int bb = a; bb < 9; ++bb) {
                float qv = stats[11 + idx]; idx++;
                QF += w[a] * w[bb] * qv * ((a == bb) ? 1.f : 2.f);
            }
        QF *= INV_NTOT;
        // conv2_b cancels in bn2 (constant shift removed by mean subtraction)
        float varc  = QF - P * P;
        float scale = bn2_g[c] * rsqrtf(varc + EPS);
        sc_s[c] = scale;
        bi_s[c] = bn2_b[c] - P * scale;
    }
    __syncthreads();

    const int r = tid >> 3, q = tid & 7;
    float v[3][6];
    #pragma unroll
    for (int di = 0; di < 3; ++di)
        #pragma unroll
        for (int j = 0; j < 6; ++j)
            v[di][j] = tile[r + di][(q << 2) + j];

    const size_t ob = ((size_t)n << 22) + (size_t)((h0b + r) << 8) + w0b + (q << 2);
    for (int c = 0; c < 64; ++c) {
        float wk[9];
        #pragma unroll
        for (int k = 0; k < 9; ++k) wk[k] = w2[c * 9 + k];
        const float sc = sc_s[c], bi = bi_s[c];
        f4_vec o;
        #pragma unroll
        for (int k = 0; k < 4; ++k) {
            float y = 0.f;
            #pragma unroll
            for (int di = 0; di < 3; ++di)
                y += wk[di * 3 + 0] * v[di][k]
                   + wk[di * 3 + 1] * v[di][k + 1]
                   + wk[di * 3 + 2] * v[di][k + 2];
            o[k] = y * sc + bi;
        }
        __builtin_nontemporal_store(o, (f4_vec*)(out + ob + ((size_t)c << 16)));
    }
}

extern "C" void kernel_launch(void* const* d_in, const int* in_sizes, int n_in,
                              void* d_out, int out_size, void* d_ws, size_t ws_size,
                              hipStream_t stream)
{
    const float* x  = (const float*)d_in[0];
    const float* w1 = (const float*)d_in[1];
    // d_in[2] = conv1_b : cancels under bn1 (training mode) -> unused
    const float* w2 = (const float*)d_in[3];
    // d_in[4] = conv2_b : cancels under bn2 -> unused
    const float* g1 = (const float*)d_in[5];
    const float* b1 = (const float*)d_in[6];
    const float* g2 = (const float*)d_in[7];
    const float* b2 = (const float*)d_in[8];
    const float* lb = (const float*)d_in[9];
    const float* ub = (const float*)d_in[10];

    float* ws  = (float*)d_ws;
    float* h0  = ws;
    float* fz  = ws + FZ_OFF;
    float* st  = ws + ST_OFF;
    float* out = (float*)d_out;

    hipMemsetAsync(st, 0, 56 * sizeof(float), stream);            // sum,sumsq,S,Q
    k1_conv1  <<<dim3(512),  dim3(512), 0, stream>>>(x, w1, h0, st);
    k3_fuzzify<<<dim3(1024), dim3(256), 0, stream>>>(h0, st, g1, b1, lb, ub, fz);
    k4_stats  <<<dim3(256),  dim3(256), 0, stream>>>(fz, st);
    k6_conv2  <<<dim3(1024), dim3(256), 0, stream>>>(fz, w2, g2, b2, st, out);
}